// Round 1
// baseline (575.832 us; speedup 1.0000x reference)
//
#include <hip/hip_runtime.h>
#include <hip/hip_bf16.h>

// Problem constants
#define B_SZ 32
#define S_SZ 512
#define D_SZ 1024
#define MEM_ROWS 2558        // MEM_LEN + N_CONV = 2048 + 510
#define OUT_ROW_STRIDE 2558
#define K_DIM 2048           // 2 taps * D
#define M_BATCH 8192         // 32 * 256
#define M_TOTAL 8448         // 8192 + 256 (254 shared rows + 2 pad)
#define N_DIM 1024

typedef _Float16 half8 __attribute__((ext_vector_type(8)));
typedef _Float16 half4v __attribute__((ext_vector_type(4)));
typedef float f32x4 __attribute__((ext_vector_type(4)));

#define LDS_STRIDE 40  // _Float16 units per LDS row (32 + 8 pad; 80B rows, 16B-aligned)

// ---------------- W transpose + f16 convert: wt[n][k] = filters[k*1024+n] ----
__global__ __launch_bounds__(256) void transpose_w(const float* __restrict__ f,
                                                   _Float16* __restrict__ wt) {
    __shared__ float tile[32][33];
    const int k0 = blockIdx.x * 32;   // 64 tiles over K=2048
    const int n0 = blockIdx.y * 32;   // 32 tiles over N=1024
    const int tx = threadIdx.x;       // 32
    const int ty = threadIdx.y;       // 8
#pragma unroll
    for (int i = 0; i < 32; i += 8)
        tile[ty + i][tx] = f[(size_t)(k0 + ty + i) * 1024 + n0 + tx];
    __syncthreads();
#pragma unroll
    for (int i = 0; i < 32; i += 8)
        wt[(size_t)(n0 + ty + i) * 2048 + k0 + tx] = (_Float16)tile[tx][ty + i];
}

// ---------------- GEMM: C[m][n] = sum_k A[m][k] * W[k][n] --------------------
// A rows: m<8192 -> inputs[b= m>>8] rows (2w, 2w+1) contiguous (w = m&255)
//         m>=8192, r=m-8192<254 -> memory rows (2r+2, 2r+3) contiguous
// Epilogue: m<8192 -> out[b][254 + w][n]; else ws_c[r][n]
__global__ __launch_bounds__(256) void gemm_kernel(const float* __restrict__ inputs,
                                                   const float* __restrict__ memory,
                                                   const _Float16* __restrict__ wt,
                                                   float* __restrict__ out,
                                                   float* __restrict__ ws_c) {
    __shared__ _Float16 a_lds[128 * LDS_STRIDE];
    __shared__ _Float16 b_lds[128 * LDS_STRIDE];

    const int tid = threadIdx.x;
    const int bm = blockIdx.x;   // 0..65
    const int bn = blockIdx.y;   // 0..7
    const int m_base = bm * 128;
    const int n_base = bn * 128;

    const int wave = tid >> 6;
    const int lane = tid & 63;
    const int q = lane >> 4;
    const int lm = lane & 15;
    const int wm = (wave >> 1) * 64;  // wave quadrant within 128x128
    const int wn = (wave & 1) * 64;

    f32x4 acc[4][4] = {};

    // Precompute A-row source pointers for the 4 staging rows this thread owns.
    const float* a_src[4];
#pragma unroll
    for (int it = 0; it < 4; ++it) {
        int pos = it * 256 + tid;
        int row = pos >> 3;              // 0..127
        int m = m_base + row;
        const float* p = nullptr;
        if (m < M_BATCH) {
            p = inputs + (size_t)(m >> 8) * (S_SZ * D_SZ) + (size_t)(m & 255) * 2048;
        } else {
            int r = m - M_BATCH;
            if (r < 254) p = memory + (size_t)(2 * r + 2) * 1024;
        }
        a_src[it] = p;
    }

    for (int kt = 0; kt < K_DIM / 32; ++kt) {
        const int k0 = kt * 32;
        __syncthreads();
        // stage A: 128 rows x 32 k, fp32 -> f16 on the fly. 4 float4 / thread.
#pragma unroll
        for (int it = 0; it < 4; ++it) {
            int pos = it * 256 + tid;
            int row = pos >> 3, c4 = pos & 7;
            float4 v = {0.f, 0.f, 0.f, 0.f};
            if (a_src[it]) v = *(const float4*)(a_src[it] + k0 + c4 * 4);
            half4v h;
            h[0] = (_Float16)v.x; h[1] = (_Float16)v.y;
            h[2] = (_Float16)v.z; h[3] = (_Float16)v.w;
            *(half4v*)(&a_lds[row * LDS_STRIDE + c4 * 4]) = h;
        }
        // stage B: 128 n-rows x 32 k f16 (from wt), 2 x 16B / thread
#pragma unroll
        for (int it = 0; it < 2; ++it) {
            int pos = it * 256 + tid;
            int row = pos >> 2, c8 = pos & 3;
            uint4 v = *(const uint4*)(wt + (size_t)(n_base + row) * 2048 + k0 + c8 * 8);
            *(uint4*)(&b_lds[row * LDS_STRIDE + c8 * 8]) = v;
        }
        __syncthreads();

        half8 a_frag[4], b_frag[4];
#pragma unroll
        for (int t = 0; t < 4; ++t) {
            a_frag[t] = *(const half8*)(&a_lds[(wm + t * 16 + lm) * LDS_STRIDE + q * 8]);
            b_frag[t] = *(const half8*)(&b_lds[(wn + t * 16 + lm) * LDS_STRIDE + q * 8]);
        }
#pragma unroll
        for (int i = 0; i < 4; ++i)
#pragma unroll
            for (int j = 0; j < 4; ++j)
                acc[i][j] = __builtin_amdgcn_mfma_f32_16x16x32_f16(a_frag[i], b_frag[j],
                                                                   acc[i][j], 0, 0, 0);
    }

    // Epilogue: C/D layout row = q*4 + reg, col = lm (verified m89/m91)
#pragma unroll
    for (int i = 0; i < 4; ++i) {
        const int m0 = m_base + wm + i * 16 + q * 4;
#pragma unroll
        for (int j = 0; j < 4; ++j) {
            const int n = n_base + wn + j * 16 + lm;
#pragma unroll
            for (int rg = 0; rg < 4; ++rg) {
                const int m = m0 + rg;
                const float v = acc[i][j][rg];
                if (m < M_BATCH) {
                    const int b = m >> 8;
                    const int row = 254 + (m & 255);
                    out[(size_t)b * (OUT_ROW_STRIDE * D_SZ) + (size_t)row * 1024 + n] = v;
                } else {
                    const int r = m - M_BATCH;
                    if (r < 254) ws_c[(size_t)r * 1024 + n] = v;
                }
            }
        }
    }
}

// ---------------- Assemble: shared-compress broadcast + memory copy + x copy -
// r (blockIdx.x) in [0, 2302): r<254 -> out row r from ws_c
//                              r<1790 -> out row 510+(r-254) from memory[1022+..]
//                              else   -> out row 2046+(r-1790) from inputs[b]
__global__ __launch_bounds__(256) void assemble_kernel(const float* __restrict__ inputs,
                                                       const float* __restrict__ memory,
                                                       const float* __restrict__ ws_c,
                                                       float* __restrict__ out) {
    const int b = blockIdx.y;
    const int r = blockIdx.x;
    const int col = threadIdx.x * 4;
    float4 v;
    size_t dst_row;
    if (r < 254) {
        v = *(const float4*)(ws_c + (size_t)r * 1024 + col);
        dst_row = r;
    } else if (r < 1790) {
        v = *(const float4*)(memory + (size_t)(1022 + r - 254) * 1024 + col);
        dst_row = 510 + (r - 254);
    } else {
        v = *(const float4*)(inputs + (size_t)b * (S_SZ * D_SZ) + (size_t)(r - 1790) * 1024 + col);
        dst_row = 2046 + (r - 1790);
    }
    *(float4*)(out + (size_t)b * (OUT_ROW_STRIDE * D_SZ) + dst_row * 1024 + col) = v;
}

extern "C" void kernel_launch(void* const* d_in, const int* in_sizes, int n_in,
                              void* d_out, int out_size, void* d_ws, size_t ws_size,
                              hipStream_t stream) {
    const float* inputs  = (const float*)d_in[0];  // (32, 512, 1024) f32
    const float* memory  = (const float*)d_in[1];  // (2558, 1024) f32
    const float* filters = (const float*)d_in[2];  // (2, 1024, 1024) f32
    float* out = (float*)d_out;

    _Float16* wt = (_Float16*)d_ws;                           // 1024 x 2048 f16 = 4 MB
    float* ws_c  = (float*)((char*)d_ws + 4 * 1024 * 1024);   // 254 x 1024 f32 ~ 1 MB

    transpose_w<<<dim3(64, 32), dim3(32, 8), 0, stream>>>(filters, wt);
    gemm_kernel<<<dim3(66, 8), 256, 0, stream>>>(inputs, memory, wt, out, ws_c);
    assemble_kernel<<<dim3(2302, 32), 256, 0, stream>>>(inputs, memory, ws_c, out);
}

// Round 2
// 519.154 us; speedup vs baseline: 1.1092x; 1.1092x over previous
//
#include <hip/hip_runtime.h>
#include <hip/hip_bf16.h>

// Problem constants
#define B_SZ 32
#define S_SZ 512
#define D_SZ 1024
#define OUT_ROW_STRIDE 2558  // MEM_LEN + N_CONV = 2048 + 510
#define K_DIM 2048           // 2 taps * D
#define M_BATCH 8192         // 32 * 256
#define M_TOTAL 8448         // 8192 + 254 shared rows + 2 pad
#define N_DIM 1024

typedef _Float16 half8 __attribute__((ext_vector_type(8)));
typedef _Float16 half4v __attribute__((ext_vector_type(4)));
typedef float f32x4 __attribute__((ext_vector_type(4)));

__device__ __forceinline__ void async_copy16(const void* g, void* l) {
    __builtin_amdgcn_global_load_lds(
        (const __attribute__((address_space(1))) unsigned int*)g,
        (__attribute__((address_space(3))) unsigned int*)l, 16, 0, 0);
}

// ---------------- W transpose + f16 convert: wt[n][k] = filters[k*1024+n] ----
__global__ __launch_bounds__(256) void transpose_w(const float* __restrict__ f,
                                                   _Float16* __restrict__ wt) {
    __shared__ float tile[32][33];
    const int k0 = blockIdx.x * 32;
    const int n0 = blockIdx.y * 32;
    const int tx = threadIdx.x;  // 32
    const int ty = threadIdx.y;  // 8
#pragma unroll
    for (int i = 0; i < 32; i += 8)
        tile[ty + i][tx] = f[(size_t)(k0 + ty + i) * 1024 + n0 + tx];
    __syncthreads();
#pragma unroll
    for (int i = 0; i < 32; i += 8)
        wt[(size_t)(n0 + ty + i) * 2048 + k0 + tx] = (_Float16)tile[tx][ty + i];
}

// ---------------- Pack A to f16: a16[m][k], m in [0,8448) ---------------------
// m<8192: inputs row slice (contiguous, == inputs + m*2048)
// 8192<=m<8446: memory rows (2r+2, 2r+3), r=m-8192
// m>=8446: zeros (pad)
__global__ __launch_bounds__(256) void convert_a(const float* __restrict__ inputs,
                                                 const float* __restrict__ memory,
                                                 _Float16* __restrict__ a16) {
    const int m = blockIdx.x;
    const int c = threadIdx.x * 8;
    const float* src = nullptr;
    if (m < M_BATCH) {
        src = inputs + (size_t)m * 2048;
    } else {
        int r = m - M_BATCH;
        if (r < 254) src = memory + (size_t)(2 * r + 2) * 1024;
    }
    half8 h;
    if (src) {
        float4 v0 = *(const float4*)(src + c);
        float4 v1 = *(const float4*)(src + c + 4);
        h[0] = (_Float16)v0.x; h[1] = (_Float16)v0.y;
        h[2] = (_Float16)v0.z; h[3] = (_Float16)v0.w;
        h[4] = (_Float16)v1.x; h[5] = (_Float16)v1.y;
        h[6] = (_Float16)v1.z; h[7] = (_Float16)v1.w;
    } else {
#pragma unroll
        for (int i = 0; i < 8; ++i) h[i] = (_Float16)0.f;
    }
    *(half8*)(a16 + (size_t)m * 2048 + c) = h;
}

// ---------------- GEMM (m97 structure): C = A16 * Wt^T -----------------------
// A tile 128x32 f16, B tile 128x32 f16, both staged via global_load_lds x16.
// LDS rows are 64B, unpadded (global_load_lds requires lane-contiguous dest).
__global__ __launch_bounds__(256) void gemm_async(const _Float16* __restrict__ a16,
                                                  const _Float16* __restrict__ wt,
                                                  float* __restrict__ out,
                                                  float* __restrict__ ws_c) {
    __shared__ _Float16 a_lds[128 * 32];
    __shared__ _Float16 b_lds[128 * 32];

    const int tid = threadIdx.x;
    const int m_base = blockIdx.x * 128;  // 66 blocks
    const int n_base = blockIdx.y * 128;  // 8 blocks

    const int wave = tid >> 6;
    const int lane = tid & 63;
    const int q = lane >> 4;
    const int lm = lane & 15;
    const int wm = (wave >> 1) * 64;
    const int wn = (wave & 1) * 64;

    // Staging map: wave w covers rows [w*16, w*16+16) of each 64-row half-tile.
    // Lane l -> row w*16 + l/4, 16B chunk l%4. LDS dest is wave-uniform base;
    // HW scatters lane l at base + l*16.
    const int srow = wave * 16 + (lane >> 2);
    const int kc = (lane & 3) * 8;  // f16 offset of this lane's 16B chunk
    const _Float16* ag0 = a16 + (size_t)(m_base + srow) * 2048 + kc;
    const _Float16* ag1 = a16 + (size_t)(m_base + 64 + srow) * 2048 + kc;
    const _Float16* bg0 = wt + (size_t)(n_base + srow) * 2048 + kc;
    const _Float16* bg1 = wt + (size_t)(n_base + 64 + srow) * 2048 + kc;
    _Float16* al0 = a_lds + wave * 512;         // 16 rows * 32 f16
    _Float16* al1 = a_lds + 2048 + wave * 512;
    _Float16* bl0 = b_lds + wave * 512;
    _Float16* bl1 = b_lds + 2048 + wave * 512;

    f32x4 acc[4][4] = {};

    for (int kt = 0; kt < K_DIM / 32; ++kt) {
        const int k0 = kt * 32;
        __syncthreads();
        async_copy16(ag0 + k0, al0);
        async_copy16(ag1 + k0, al1);
        async_copy16(bg0 + k0, bl0);
        async_copy16(bg1 + k0, bl1);
        __syncthreads();

        half8 a_frag[4], b_frag[4];
#pragma unroll
        for (int t = 0; t < 4; ++t) {
            a_frag[t] = *(const half8*)(&a_lds[(wm + t * 16 + lm) * 32 + q * 8]);
            b_frag[t] = *(const half8*)(&b_lds[(wn + t * 16 + lm) * 32 + q * 8]);
        }
#pragma unroll
        for (int i = 0; i < 4; ++i)
#pragma unroll
            for (int j = 0; j < 4; ++j)
                acc[i][j] = __builtin_amdgcn_mfma_f32_16x16x32_f16(a_frag[i], b_frag[j],
                                                                   acc[i][j], 0, 0, 0);
    }

    // Epilogue: C/D layout row = q*4 + reg, col = lm (verified, round 1 passed)
#pragma unroll
    for (int i = 0; i < 4; ++i) {
        const int m0 = m_base + wm + i * 16 + q * 4;
#pragma unroll
        for (int j = 0; j < 4; ++j) {
            const int n = n_base + wn + j * 16 + lm;
#pragma unroll
            for (int rg = 0; rg < 4; ++rg) {
                const int m = m0 + rg;
                const float v = acc[i][j][rg];
                if (m < M_BATCH) {
                    const int b = m >> 8;
                    const int row = 254 + (m & 255);
                    out[(size_t)b * (OUT_ROW_STRIDE * D_SZ) + (size_t)row * 1024 + n] = v;
                } else {
                    const int r = m - M_BATCH;
                    if (r < 254) ws_c[(size_t)r * 1024 + n] = v;
                }
            }
        }
    }
}

// ---------------- Fallback GEMM (round-1, fp32 A in-loop convert) ------------
#define LDS_STRIDE 40
__global__ __launch_bounds__(256) void gemm_fallback(const float* __restrict__ inputs,
                                                     const float* __restrict__ memory,
                                                     const _Float16* __restrict__ wt,
                                                     float* __restrict__ out,
                                                     float* __restrict__ ws_c) {
    __shared__ _Float16 a_lds[128 * LDS_STRIDE];
    __shared__ _Float16 b_lds[128 * LDS_STRIDE];
    const int tid = threadIdx.x;
    const int m_base = blockIdx.x * 128;
    const int n_base = blockIdx.y * 128;
    const int wave = tid >> 6, lane = tid & 63;
    const int q = lane >> 4, lm = lane & 15;
    const int wm = (wave >> 1) * 64, wn = (wave & 1) * 64;
    f32x4 acc[4][4] = {};
    const float* a_src[4];
#pragma unroll
    for (int it = 0; it < 4; ++it) {
        int pos = it * 256 + tid;
        int row = pos >> 3;
        int m = m_base + row;
        const float* p = nullptr;
        if (m < M_BATCH) p = inputs + (size_t)m * 2048;
        else { int r = m - M_BATCH; if (r < 254) p = memory + (size_t)(2 * r + 2) * 1024; }
        a_src[it] = p;
    }
    for (int kt = 0; kt < K_DIM / 32; ++kt) {
        const int k0 = kt * 32;
        __syncthreads();
#pragma unroll
        for (int it = 0; it < 4; ++it) {
            int pos = it * 256 + tid;
            int row = pos >> 3, c4 = pos & 7;
            float4 v = {0.f, 0.f, 0.f, 0.f};
            if (a_src[it]) v = *(const float4*)(a_src[it] + k0 + c4 * 4);
            half4v h;
            h[0] = (_Float16)v.x; h[1] = (_Float16)v.y;
            h[2] = (_Float16)v.z; h[3] = (_Float16)v.w;
            *(half4v*)(&a_lds[row * LDS_STRIDE + c4 * 4]) = h;
        }
#pragma unroll
        for (int it = 0; it < 2; ++it) {
            int pos = it * 256 + tid;
            int row = pos >> 2, c8 = pos & 3;
            uint4 v = *(const uint4*)(wt + (size_t)(n_base + row) * 2048 + k0 + c8 * 8);
            *(uint4*)(&b_lds[row * LDS_STRIDE + c8 * 8]) = v;
        }
        __syncthreads();
        half8 a_frag[4], b_frag[4];
#pragma unroll
        for (int t = 0; t < 4; ++t) {
            a_frag[t] = *(const half8*)(&a_lds[(wm + t * 16 + lm) * LDS_STRIDE + q * 8]);
            b_frag[t] = *(const half8*)(&b_lds[(wn + t * 16 + lm) * LDS_STRIDE + q * 8]);
        }
#pragma unroll
        for (int i = 0; i < 4; ++i)
#pragma unroll
            for (int j = 0; j < 4; ++j)
                acc[i][j] = __builtin_amdgcn_mfma_f32_16x16x32_f16(a_frag[i], b_frag[j],
                                                                   acc[i][j], 0, 0, 0);
    }
#pragma unroll
    for (int i = 0; i < 4; ++i) {
        const int m0 = m_base + wm + i * 16 + q * 4;
#pragma unroll
        for (int j = 0; j < 4; ++j) {
            const int n = n_base + wn + j * 16 + lm;
#pragma unroll
            for (int rg = 0; rg < 4; ++rg) {
                const int m = m0 + rg;
                const float v = acc[i][j][rg];
                if (m < M_BATCH) {
                    const int b = m >> 8;
                    const int row = 254 + (m & 255);
                    out[(size_t)b * (OUT_ROW_STRIDE * D_SZ) + (size_t)row * 1024 + n] = v;
                } else {
                    const int r = m - M_BATCH;
                    if (r < 254) ws_c[(size_t)r * 1024 + n] = v;
                }
            }
        }
    }
}

// ---------------- Assemble -------------------------------------------------
__global__ __launch_bounds__(256) void assemble_kernel(const float* __restrict__ inputs,
                                                       const float* __restrict__ memory,
                                                       const float* __restrict__ ws_c,
                                                       float* __restrict__ out) {
    const int b = blockIdx.y;
    const int r = blockIdx.x;
    const int col = threadIdx.x * 4;
    float4 v;
    size_t dst_row;
    if (r < 254) {
        v = *(const float4*)(ws_c + (size_t)r * 1024 + col);
        dst_row = r;
    } else if (r < 1790) {
        v = *(const float4*)(memory + (size_t)(1022 + r - 254) * 1024 + col);
        dst_row = 510 + (r - 254);
    } else {
        v = *(const float4*)(inputs + (size_t)b * (S_SZ * D_SZ) + (size_t)(r - 1790) * 1024 + col);
        dst_row = 2046 + (r - 1790);
    }
    *(float4*)(out + (size_t)b * (OUT_ROW_STRIDE * D_SZ) + dst_row * 1024 + col) = v;
}

extern "C" void kernel_launch(void* const* d_in, const int* in_sizes, int n_in,
                              void* d_out, int out_size, void* d_ws, size_t ws_size,
                              hipStream_t stream) {
    const float* inputs  = (const float*)d_in[0];  // (32, 512, 1024) f32
    const float* memory  = (const float*)d_in[1];  // (2558, 1024) f32
    const float* filters = (const float*)d_in[2];  // (2, 1024, 1024) f32
    float* out = (float*)d_out;

    // ws layout: wt (4 MB) | a16 (34.6 MB) | ws_c (~1 MB)
    const size_t WT_BYTES  = (size_t)N_DIM * K_DIM * 2;           // 4 MB
    const size_t A16_BYTES = (size_t)M_TOTAL * K_DIM * 2;         // 34.6 MB
    const size_t NEED = WT_BYTES + A16_BYTES + (size_t)254 * 1024 * 4;

    _Float16* wt = (_Float16*)d_ws;
    transpose_w<<<dim3(64, 32), dim3(32, 8), 0, stream>>>(filters, wt);

    if (ws_size >= NEED) {
        _Float16* a16 = (_Float16*)((char*)d_ws + WT_BYTES);
        float* ws_c   = (float*)((char*)d_ws + WT_BYTES + A16_BYTES);
        convert_a<<<dim3(M_TOTAL), 256, 0, stream>>>(inputs, memory, a16);
        gemm_async<<<dim3(66, 8), 256, 0, stream>>>(a16, wt, out, ws_c);
        assemble_kernel<<<dim3(2302, 32), 256, 0, stream>>>(inputs, memory, ws_c, out);
    } else {
        float* ws_c = (float*)((char*)d_ws + WT_BYTES);
        gemm_fallback<<<dim3(66, 8), 256, 0, stream>>>(inputs, memory, wt, out, ws_c);
        assemble_kernel<<<dim3(2302, 32), 256, 0, stream>>>(inputs, memory, ws_c, out);
    }
}

// Round 3
// 482.425 us; speedup vs baseline: 1.1936x; 1.0761x over previous
//
#include <hip/hip_runtime.h>
#include <hip/hip_bf16.h>

// Problem constants
#define B_SZ 32
#define S_SZ 512
#define D_SZ 1024
#define OUT_ROW_STRIDE 2558  // MEM_LEN + N_CONV = 2048 + 510
#define K_DIM 2048           // 2 taps * D
#define M_BATCH 8192         // 32 * 256
#define M_TOTAL 8448         // 8192 + 254 shared rows + 2 pad
#define N_DIM 1024

typedef _Float16 half8 __attribute__((ext_vector_type(8)));
typedef _Float16 half4v __attribute__((ext_vector_type(4)));
typedef float f32x4 __attribute__((ext_vector_type(4)));

__device__ __forceinline__ void async_copy16(const void* g, void* l) {
    __builtin_amdgcn_global_load_lds(
        (const __attribute__((address_space(1))) unsigned int*)g,
        (__attribute__((address_space(3))) unsigned int*)l, 16, 0, 0);
}

// ---------------- W transpose + f16 convert: wt[n][k] = filters[k*1024+n] ----
__global__ __launch_bounds__(256) void transpose_w(const float* __restrict__ f,
                                                   _Float16* __restrict__ wt) {
    __shared__ float tile[32][33];
    const int k0 = blockIdx.x * 32;
    const int n0 = blockIdx.y * 32;
    const int tx = threadIdx.x;  // 32
    const int ty = threadIdx.y;  // 8
#pragma unroll
    for (int i = 0; i < 32; i += 8)
        tile[ty + i][tx] = f[(size_t)(k0 + ty + i) * 1024 + n0 + tx];
    __syncthreads();
#pragma unroll
    for (int i = 0; i < 32; i += 8)
        wt[(size_t)(n0 + ty + i) * 2048 + k0 + tx] = (_Float16)tile[tx][ty + i];
}

// ---------------- Pack A to f16 + fused x->out copy --------------------------
// a16[m][k]: m<8192 -> inputs row slice (contiguous); 8192<=m<8446 -> memory
// rows (2r+2, 2r+3); m>=8446 -> zeros.
// Fused: for m<8192 also writes inputs rows to out[b][2046 + 2w + hi] (fp32),
// saving a second read of `inputs` in the assemble pass.
__global__ __launch_bounds__(256) void convert_a(const float* __restrict__ inputs,
                                                 const float* __restrict__ memory,
                                                 _Float16* __restrict__ a16,
                                                 float* __restrict__ out) {
    const int m = blockIdx.x;
    const int t = threadIdx.x;
    const int c = t * 8;
    const float* src = nullptr;
    bool is_batch = false;
    if (m < M_BATCH) {
        src = inputs + (size_t)m * 2048;
        is_batch = true;
    } else {
        int r = m - M_BATCH;
        if (r < 254) src = memory + (size_t)(2 * r + 2) * 1024;
    }
    half8 h;
    if (src) {
        float4 v0 = *(const float4*)(src + c);
        float4 v1 = *(const float4*)(src + c + 4);
        h[0] = (_Float16)v0.x; h[1] = (_Float16)v0.y;
        h[2] = (_Float16)v0.z; h[3] = (_Float16)v0.w;
        h[4] = (_Float16)v1.x; h[5] = (_Float16)v1.y;
        h[6] = (_Float16)v1.z; h[7] = (_Float16)v1.w;
        if (is_batch) {
            const int b = m >> 8;
            const int w = m & 255;
            const int hi = t >> 7;            // which of the two src rows
            const int col = (t & 127) * 8;    // column within that row
            float* dst = out + (size_t)b * (OUT_ROW_STRIDE * D_SZ)
                             + (size_t)(2046 + 2 * w + hi) * 1024 + col;
            *(float4*)dst = v0;
            *(float4*)(dst + 4) = v1;
        }
    } else {
#pragma unroll
        for (int i = 0; i < 8; ++i) h[i] = (_Float16)0.f;
    }
    *(half8*)(a16 + (size_t)m * 2048 + c) = h;
}

// ---------------- GEMM: BM=128 BN=64 BK=64, XOR-swizzled LDS -----------------
// Grid (66, 16) = 1056 blocks (~4.1/CU). LDS rows are 64 f16 = 128 B = 8
// 16B-units; unit u of row r holds global unit u^(r&7) (swizzle applied on the
// global side of global_load_lds, and on the ds_read address) -> conflict-free.
__global__ __launch_bounds__(256, 4) void gemm_async(const _Float16* __restrict__ a16,
                                                     const _Float16* __restrict__ wt,
                                                     float* __restrict__ out,
                                                     float* __restrict__ ws_c) {
    __shared__ _Float16 a_lds[128 * 64];  // 16 KB
    __shared__ _Float16 b_lds[64 * 64];   // 8 KB

    const int tid = threadIdx.x;
    const int m_base = blockIdx.x * 128;  // 66
    const int n_base = blockIdx.y * 64;   // 16

    const int wave = tid >> 6;
    const int lane = tid & 63;
    const int q = lane >> 4;        // 0..3
    const int lm = lane & 15;
    const int wm = (wave >> 1) * 64;  // wave tile 64(m) x 32(n)
    const int wn = (wave & 1) * 32;

    // --- staging maps (global side carries the swizzle) ---
    const int srow = lane >> 3;                    // 0..7 within an 8-row op
    const int g = (lane & 7) ^ srow;               // swizzled 16B-unit index
    const int koff = g * 8;                        // f16 offset within row

    const _Float16* ag[4];
    _Float16* al[4];
#pragma unroll
    for (int i = 0; i < 4; ++i) {
        int row = wave * 32 + i * 8 + srow;
        ag[i] = a16 + (size_t)(m_base + row) * 2048 + koff;
        al[i] = a_lds + (wave * 32 + i * 8) * 64;
    }
    const _Float16* bg[2];
    _Float16* bl[2];
#pragma unroll
    for (int i = 0; i < 2; ++i) {
        int row = wave * 16 + i * 8 + srow;
        bg[i] = wt + (size_t)(n_base + row) * 2048 + koff;
        bl[i] = b_lds + (wave * 16 + i * 8) * 64;
    }

    f32x4 acc[4][2] = {};

    // fragment-read swizzle: phys_unit = (h*4 + q) ^ (row & 7); row&7 == lm&7
    const int sw = lm & 7;

    for (int kt = 0; kt < K_DIM / 64; ++kt) {
        const int k0 = kt * 64;
        __syncthreads();
#pragma unroll
        for (int i = 0; i < 4; ++i) async_copy16(ag[i] + k0, al[i]);
#pragma unroll
        for (int i = 0; i < 2; ++i) async_copy16(bg[i] + k0, bl[i]);
        __syncthreads();

#pragma unroll
        for (int h = 0; h < 2; ++h) {
            const int phys = ((h * 4 + q) ^ sw) * 8;
            half8 a_frag[4], b_frag[2];
#pragma unroll
            for (int t = 0; t < 4; ++t)
                a_frag[t] = *(const half8*)(&a_lds[(wm + t * 16 + lm) * 64 + phys]);
#pragma unroll
            for (int u = 0; u < 2; ++u)
                b_frag[u] = *(const half8*)(&b_lds[(wn + u * 16 + lm) * 64 + phys]);
#pragma unroll
            for (int t = 0; t < 4; ++t)
#pragma unroll
                for (int u = 0; u < 2; ++u)
                    acc[t][u] = __builtin_amdgcn_mfma_f32_16x16x32_f16(
                        a_frag[t], b_frag[u], acc[t][u], 0, 0, 0);
        }
    }

    // Epilogue: C/D layout row = q*4 + reg, col = lm (verified rounds 1-2)
#pragma unroll
    for (int t = 0; t < 4; ++t) {
        const int m0 = m_base + wm + t * 16 + q * 4;
#pragma unroll
        for (int u = 0; u < 2; ++u) {
            const int n = n_base + wn + u * 16 + lm;
#pragma unroll
            for (int rg = 0; rg < 4; ++rg) {
                const int m = m0 + rg;
                const float v = acc[t][u][rg];
                if (m < M_BATCH) {
                    const int b = m >> 8;
                    const int row = 254 + (m & 255);
                    out[(size_t)b * (OUT_ROW_STRIDE * D_SZ) + (size_t)row * 1024 + n] = v;
                } else {
                    const int r = m - M_BATCH;
                    if (r < 254) ws_c[(size_t)r * 1024 + n] = v;
                }
            }
        }
    }
}

// ---------------- Assemble (small): shared-compress bcast + memory copy ------
// r<254 -> out row r from ws_c; else out row 510+(r-254) from memory[1022+..]
__global__ __launch_bounds__(256) void assemble_small(const float* __restrict__ memory,
                                                      const float* __restrict__ ws_c,
                                                      float* __restrict__ out) {
    const int b = blockIdx.y;
    const int r = blockIdx.x;
    const int col = threadIdx.x * 4;
    float4 v;
    size_t dst_row;
    if (r < 254) {
        v = *(const float4*)(ws_c + (size_t)r * 1024 + col);
        dst_row = r;
    } else {
        v = *(const float4*)(memory + (size_t)(1022 + r - 254) * 1024 + col);
        dst_row = 510 + (r - 254);
    }
    *(float4*)(out + (size_t)b * (OUT_ROW_STRIDE * D_SZ) + dst_row * 1024 + col) = v;
}

// ---------------- Fallback GEMM (round-1 style, no ws for a16) ---------------
#define LDS_STRIDE 40
__global__ __launch_bounds__(256) void gemm_fallback(const float* __restrict__ inputs,
                                                     const float* __restrict__ memory,
                                                     const _Float16* __restrict__ wt,
                                                     float* __restrict__ out,
                                                     float* __restrict__ ws_c) {
    __shared__ _Float16 a_lds[128 * LDS_STRIDE];
    __shared__ _Float16 b_lds[128 * LDS_STRIDE];
    const int tid = threadIdx.x;
    const int m_base = blockIdx.x * 128;
    const int n_base = blockIdx.y * 128;
    const int wave = tid >> 6, lane = tid & 63;
    const int q = lane >> 4, lm = lane & 15;
    const int wm = (wave >> 1) * 64, wn = (wave & 1) * 64;
    f32x4 acc[4][4] = {};
    const float* a_src[4];
#pragma unroll
    for (int it = 0; it < 4; ++it) {
        int pos = it * 256 + tid;
        int row = pos >> 3;
        int m = m_base + row;
        const float* p = nullptr;
        if (m < M_BATCH) p = inputs + (size_t)m * 2048;
        else { int r = m - M_BATCH; if (r < 254) p = memory + (size_t)(2 * r + 2) * 1024; }
        a_src[it] = p;
    }
    for (int kt = 0; kt < K_DIM / 32; ++kt) {
        const int k0 = kt * 32;
        __syncthreads();
#pragma unroll
        for (int it = 0; it < 4; ++it) {
            int pos = it * 256 + tid;
            int row = pos >> 3, c4 = pos & 7;
            float4 v = {0.f, 0.f, 0.f, 0.f};
            if (a_src[it]) v = *(const float4*)(a_src[it] + k0 + c4 * 4);
            half4v h;
            h[0] = (_Float16)v.x; h[1] = (_Float16)v.y;
            h[2] = (_Float16)v.z; h[3] = (_Float16)v.w;
            *(half4v*)(&a_lds[row * LDS_STRIDE + c4 * 4]) = h;
        }
#pragma unroll
        for (int it = 0; it < 2; ++it) {
            int pos = it * 256 + tid;
            int row = pos >> 2, c8 = pos & 3;
            uint4 v = *(const uint4*)(wt + (size_t)(n_base + row) * 2048 + k0 + c8 * 8);
            *(uint4*)(&b_lds[row * LDS_STRIDE + c8 * 8]) = v;
        }
        __syncthreads();
        half8 a_frag[4], b_frag[4];
#pragma unroll
        for (int t = 0; t < 4; ++t) {
            a_frag[t] = *(const half8*)(&a_lds[(wm + t * 16 + lm) * LDS_STRIDE + q * 8]);
            b_frag[t] = *(const half8*)(&b_lds[(wn + t * 16 + lm) * LDS_STRIDE + q * 8]);
        }
#pragma unroll
        for (int i = 0; i < 4; ++i)
#pragma unroll
            for (int j = 0; j < 4; ++j)
                acc[i][j] = __builtin_amdgcn_mfma_f32_16x16x32_f16(a_frag[i], b_frag[j],
                                                                   acc[i][j], 0, 0, 0);
    }
#pragma unroll
    for (int i = 0; i < 4; ++i) {
        const int m0 = m_base + wm + i * 16 + q * 4;
#pragma unroll
        for (int j = 0; j < 4; ++j) {
            const int n = n_base + wn + j * 16 + lm;
#pragma unroll
            for (int rg = 0; rg < 4; ++rg) {
                const int m = m0 + rg;
                const float v = acc[i][j][rg];
                if (m < M_BATCH) {
                    const int b = m >> 8;
                    const int row = 254 + (m & 255);
                    out[(size_t)b * (OUT_ROW_STRIDE * D_SZ) + (size_t)row * 1024 + n] = v;
                } else {
                    const int r = m - M_BATCH;
                    if (r < 254) ws_c[(size_t)r * 1024 + n] = v;
                }
            }
        }
    }
}

// ---------------- Fallback assemble (also copies x rows) ---------------------
__global__ __launch_bounds__(256) void assemble_full(const float* __restrict__ inputs,
                                                     const float* __restrict__ memory,
                                                     const float* __restrict__ ws_c,
                                                     float* __restrict__ out) {
    const int b = blockIdx.y;
    const int r = blockIdx.x;
    const int col = threadIdx.x * 4;
    float4 v;
    size_t dst_row;
    if (r < 254) {
        v = *(const float4*)(ws_c + (size_t)r * 1024 + col);
        dst_row = r;
    } else if (r < 1790) {
        v = *(const float4*)(memory + (size_t)(1022 + r - 254) * 1024 + col);
        dst_row = 510 + (r - 254);
    } else {
        v = *(const float4*)(inputs + (size_t)b * (S_SZ * D_SZ) + (size_t)(r - 1790) * 1024 + col);
        dst_row = 2046 + (r - 1790);
    }
    *(float4*)(out + (size_t)b * (OUT_ROW_STRIDE * D_SZ) + dst_row * 1024 + col) = v;
}

extern "C" void kernel_launch(void* const* d_in, const int* in_sizes, int n_in,
                              void* d_out, int out_size, void* d_ws, size_t ws_size,
                              hipStream_t stream) {
    const float* inputs  = (const float*)d_in[0];  // (32, 512, 1024) f32
    const float* memory  = (const float*)d_in[1];  // (2558, 1024) f32
    const float* filters = (const float*)d_in[2];  // (2, 1024, 1024) f32
    float* out = (float*)d_out;

    // ws layout: wt (4 MB) | a16 (34.6 MB) | ws_c (~1 MB)
    const size_t WT_BYTES  = (size_t)N_DIM * K_DIM * 2;
    const size_t A16_BYTES = (size_t)M_TOTAL * K_DIM * 2;
    const size_t NEED = WT_BYTES + A16_BYTES + (size_t)254 * 1024 * 4;

    _Float16* wt = (_Float16*)d_ws;
    transpose_w<<<dim3(64, 32), dim3(32, 8), 0, stream>>>(filters, wt);

    if (ws_size >= NEED) {
        _Float16* a16 = (_Float16*)((char*)d_ws + WT_BYTES);
        float* ws_c   = (float*)((char*)d_ws + WT_BYTES + A16_BYTES);
        convert_a<<<dim3(M_TOTAL), 256, 0, stream>>>(inputs, memory, a16, out);
        gemm_async<<<dim3(66, 16), 256, 0, stream>>>(a16, wt, out, ws_c);
        assemble_small<<<dim3(1790, 32), 256, 0, stream>>>(memory, ws_c, out);
    } else {
        float* ws_c = (float*)((char*)d_ws + WT_BYTES);
        gemm_fallback<<<dim3(66, 8), 256, 0, stream>>>(inputs, memory, wt, out, ws_c);
        assemble_full<<<dim3(2302, 32), 256, 0, stream>>>(inputs, memory, ws_c, out);
    }
}